// Round 2
// baseline (157.894 us; speedup 1.0000x reference)
//
#include <hip/hip_runtime.h>

#define QSTEP 25.5f
#define DZ (85.0f/512.0f)

__device__ __forceinline__ void mm_step(float4 a, float4 b, float acc[4][4]) {
  float ax[4] = {a.x, a.y, a.z, a.w};
  float bx[4] = {b.x, b.y, b.z, b.w};
#pragma unroll
  for (int i = 0; i < 4; ++i)
#pragma unroll
    for (int j = 0; j < 4; ++j)
      acc[i][j] = fmaf(ax[i], bx[j], acc[i][j]);
}

// One wave per 32x32 tile. Lane (rg,cg) owns the 4x4 output block at rows
// 4*rg..+3, cols 4*cg..+3. Every matmul reads A transposed (stride 36 pad ->
// conflict-free b128 row-segment reads) and B row-major.
//
// Reference semantics (derived from einsum strings, NOT the comments):
//   coeff = C @ X @ C^T ; W = quant(coeff) ; rec = (C @ W @ C) / 1023
__global__ __launch_bounds__(256, 3) void vvc_dct_quant_kernel(
    const float* __restrict__ resid,
    const float* __restrict__ dct,
    const float* __restrict__ cshift,
    float* __restrict__ out)
{
  __shared__ float lds[11584];   // 4 waves * 2304 + C(1152) + CT(1152) + shift(64)
  const int tid  = threadIdx.x;
  const int wave = tid >> 6;
  const int lane = tid & 63;
  const int rg = lane >> 3;      // 0..7 output row group
  const int cg = lane & 7;       // 0..7 output col group

  float* BufA = lds + wave * 2304;   // stride-36 transposed intermediate (tmpT / UT)
  float* BufB = BufA + 1152;         // X packed stride-32, then W stride-36
  float* Cb   = lds + 9216;          // C rows, stride 36
  float* CTb  = lds + 10368;         // C^T rows, stride 36
  float* Sh   = lds + 11520;         // coeff_shift table

  // ---- stage C, C^T, shift table (block-cooperative, once)
  {
    float4 cv = reinterpret_cast<const float4*>(dct)[tid];
    int r  = tid >> 3;
    int c0 = (tid & 7) * 4;
    *reinterpret_cast<float4*>(Cb + r * 36 + c0) = cv;
    CTb[(c0 + 0) * 36 + r] = cv.x;
    CTb[(c0 + 1) * 36 + r] = cv.y;
    CTb[(c0 + 2) * 36 + r] = cv.z;
    CTb[(c0 + 3) * 36 + r] = cv.w;
    if (tid < 64) Sh[tid] = cshift[tid];
  }
  __syncthreads();

  const int tile = blockIdx.x * 4 + wave;
  const float* gx = resid + (size_t)tile * 1024;
  float* gout     = out   + (size_t)tile * 1024;

  // ---- stage X * 1023 into BufB (packed stride-32; row reads are conflict-free)
#pragma unroll
  for (int m = 0; m < 4; ++m) {
    float4 v = reinterpret_cast<const float4*>(gx)[lane + 64 * m];
    v.x *= 1023.0f; v.y *= 1023.0f; v.z *= 1023.0f; v.w *= 1023.0f;
    reinterpret_cast<float4*>(BufB)[lane + 64 * m] = v;
  }

  float acc[4][4];

  // ---- stage 1: tmp = C @ X    (A^T = CTb, B = X stride 32)
#pragma unroll
  for (int i = 0; i < 4; ++i)
#pragma unroll
    for (int j = 0; j < 4; ++j) acc[i][j] = 0.0f;
#pragma unroll 8
  for (int t = 0; t < 32; ++t) {
    float4 a = *reinterpret_cast<const float4*>(CTb  + t * 36 + rg * 4);
    float4 b = *reinterpret_cast<const float4*>(BufB + t * 32 + cg * 4);
    mm_step(a, b, acc);
  }
  // write tmp^T into BufA
#pragma unroll
  for (int j = 0; j < 4; ++j) {
    float4 v = make_float4(acc[0][j], acc[1][j], acc[2][j], acc[3][j]);
    *reinterpret_cast<float4*>(BufA + (cg * 4 + j) * 36 + rg * 4) = v;
  }

  // ---- stage 2: coeff = tmp @ C^T   (A^T = tmpT in BufA, B = CTb)
#pragma unroll
  for (int i = 0; i < 4; ++i)
#pragma unroll
    for (int j = 0; j < 4; ++j) acc[i][j] = 0.0f;
#pragma unroll 8
  for (int t = 0; t < 32; ++t) {
    float4 a = *reinterpret_cast<const float4*>(BufA + t * 36 + rg * 4);
    float4 b = *reinterpret_cast<const float4*>(CTb  + t * 36 + cg * 4);
    mm_step(a, b, acc);
  }

  // ---- dead-zone quantize + dequant (forward value of the STE pair)
  // q_abs = floor(|c|/QSTEP + DZ); cs = coeff_shift[min(q,63)];
  // cah = q<64 ? ((1024-cs)*q*QSTEP + cs*(q+1)*QSTEP)/1024 : q*QSTEP; sign of c.
#pragma unroll
  for (int i = 0; i < 4; ++i) {
#pragma unroll
    for (int j = 0; j < 4; ++j) {
      float c   = acc[i][j];
      float qa  = floorf(fabsf(c) / QSTEP + DZ);
      float ca  = qa * QSTEP;
      int   qi  = (int)qa; qi = qi > 63 ? 63 : qi;
      float cs  = Sh[qi];
      float ca2 = (qa + 1.0f) * QSTEP;
      float corr = ((1024.0f - cs) * ca + cs * ca2) * (1.0f / 1024.0f);
      float cah  = (qa < 64.0f) ? corr : ca;
      acc[i][j]  = (c < 0.0f) ? -cah : cah;
    }
    // write W row-major into BufB (stride 36) for stage 3
    float4 v = make_float4(acc[i][0], acc[i][1], acc[i][2], acc[i][3]);
    *reinterpret_cast<float4*>(BufB + (rg * 4 + i) * 36 + cg * 4) = v;
  }

  // ---- stage 3: U = C @ W   (einsum 'hk,bckw->bchw' => LEFT factor is C,
  //      not C^T as the reference comment claims!)  A^T = C^T rows = CTb.
#pragma unroll
  for (int i = 0; i < 4; ++i)
#pragma unroll
    for (int j = 0; j < 4; ++j) acc[i][j] = 0.0f;
#pragma unroll 8
  for (int t = 0; t < 32; ++t) {
    float4 a = *reinterpret_cast<const float4*>(CTb  + t * 36 + rg * 4);
    float4 b = *reinterpret_cast<const float4*>(BufB + t * 36 + cg * 4);
    mm_step(a, b, acc);
  }
  // write U^T into BufA (tmpT dead now)
#pragma unroll
  for (int j = 0; j < 4; ++j) {
    float4 v = make_float4(acc[0][j], acc[1][j], acc[2][j], acc[3][j]);
    *reinterpret_cast<float4*>(BufA + (cg * 4 + j) * 36 + rg * 4) = v;
  }

  // ---- stage 4: R = U @ C   (A^T = UT in BufA, B = Cb)
#pragma unroll
  for (int i = 0; i < 4; ++i)
#pragma unroll
    for (int j = 0; j < 4; ++j) acc[i][j] = 0.0f;
#pragma unroll 8
  for (int t = 0; t < 32; ++t) {
    float4 a = *reinterpret_cast<const float4*>(BufA + t * 36 + rg * 4);
    float4 b = *reinterpret_cast<const float4*>(Cb   + t * 36 + cg * 4);
    mm_step(a, b, acc);
  }

  // ---- output: /1023, coalesced float4 stores
#pragma unroll
  for (int i = 0; i < 4; ++i) {
    float4 v = make_float4(acc[i][0] * (1.0f / 1023.0f),
                           acc[i][1] * (1.0f / 1023.0f),
                           acc[i][2] * (1.0f / 1023.0f),
                           acc[i][3] * (1.0f / 1023.0f));
    *reinterpret_cast<float4*>(gout + (rg * 4 + i) * 32 + cg * 4) = v;
  }
}

extern "C" void kernel_launch(void* const* d_in, const int* in_sizes, int n_in,
                              void* d_out, int out_size, void* d_ws, size_t ws_size,
                              hipStream_t stream) {
  const float* resid  = (const float*)d_in[0];   // [256,64,32,32]
  const float* dct    = (const float*)d_in[1];   // [32,32]
  const float* cshift = (const float*)d_in[2];   // [64]
  float* out = (float*)d_out;

  int tiles  = out_size / 1024;   // 16384
  int blocks = tiles / 4;         // 4 tiles (waves) per 256-thread block
  vvc_dct_quant_kernel<<<blocks, 256, 0, stream>>>(resid, dct, cshift, out);
}

// Round 3
// 119.386 us; speedup vs baseline: 1.3225x; 1.3225x over previous
//
#include <hip/hip_runtime.h>

typedef float f32x4 __attribute__((ext_vector_type(4)));
typedef short s16x8 __attribute__((ext_vector_type(8)));   // 8 bf16 in 4 VGPRs

#define QSTEP 25.5f
#define DZ (85.0f/512.0f)

// round-to-nearest-even fp32 -> bf16 (returns low-16 bits)
__device__ __forceinline__ unsigned rne_bf16(float x) {
  unsigned u = __float_as_uint(x);
  return (u + 0x7FFFu + ((u >> 16) & 1u)) >> 16;
}
// packed split: low16 = bf16(hi), high16 = bf16(x - hi)
__device__ __forceinline__ unsigned pack_split(float x) {
  unsigned hi = rne_bf16(x);
  float r = x - __uint_as_float(hi << 16);
  unsigned lo = rne_bf16(r);
  return hi | (lo << 16);
}
__device__ __forceinline__ s16x8 unpack_hi(uint4 a, uint4 b) {
  s16x8 v;
  v[0]=(short)a.x; v[1]=(short)a.y; v[2]=(short)a.z; v[3]=(short)a.w;
  v[4]=(short)b.x; v[5]=(short)b.y; v[6]=(short)b.z; v[7]=(short)b.w;
  return v;
}
__device__ __forceinline__ s16x8 unpack_lo(uint4 a, uint4 b) {
  s16x8 v;
  v[0]=(short)(a.x>>16); v[1]=(short)(a.y>>16); v[2]=(short)(a.z>>16); v[3]=(short)(a.w>>16);
  v[4]=(short)(b.x>>16); v[5]=(short)(b.y>>16); v[6]=(short)(b.z>>16); v[7]=(short)(b.w>>16);
  return v;
}

// One wave per 32x32 tile, 2x2 grid of 16x16x32 bf16 MFMAs per matmul.
// Semantics: coeff = C@X@C^T ; W = quant(coeff) ; rec = (C@W@C)/1023.
// Formulated so C is always the static-register operand:
//   S1: tmp = C @ X        (A=C hi+lo, B=X^T rows, 3 products)
//   S2: coeff^T = C @ tmp^T(A=C hi+lo, B=tmp rows, 3 products)
//   S3: tmp2 = C @ W       (A=C hi,    B=W^T rows, 1 product)
//   S4: rec = tmp2 @ C     (A=tmp2,    B=C^T static, 1 product)
// MFMA maps [verified]: A[m=lane&15][k=quad*8+j]; B[k=quad*8+j][n=lane&15];
//                       D[row=quad*4+r][col=lane&15].
__global__ __launch_bounds__(256, 4) void vvc_mfma_kernel(
    const float* __restrict__ resid,
    const float* __restrict__ dct,
    const float* __restrict__ cshift,
    float* __restrict__ out)
{
  __shared__ unsigned shm[64 + 4 * 1152];   // Sh(64w) + 4 wave buffers [32][36]
  float* Sh = (float*)shm;
  unsigned* Pall = shm + 64;

  const int tid  = threadIdx.x;
  const int wave = tid >> 6;
  const int lane = tid & 63;
  const int col  = lane & 15;     // m/n index within a 16-tile
  const int quad = lane >> 4;     // 0..3
  const int k0   = quad * 8;      // k-base of this lane's fragment

  // ---- init: packed-split C (row-major [k][h]) and C^T ([h][k]) staged in
  // LDS (overlapping wave0/wave1 buffers, dead after static-frag loads)
  unsigned* Cpk  = Pall;
  unsigned* CTpk = Pall + 1152;
  {
    float4 cv = ((const float4*)dct)[tid];   // C[k][h..h+3]
    int k = tid >> 3, h = (tid & 7) * 4;
    unsigned p0 = pack_split(cv.x), p1 = pack_split(cv.y);
    unsigned p2 = pack_split(cv.z), p3 = pack_split(cv.w);
    Cpk[k*36 + h+0] = p0; Cpk[k*36 + h+1] = p1;
    Cpk[k*36 + h+2] = p2; Cpk[k*36 + h+3] = p3;
    CTpk[(h+0)*36 + k] = p0; CTpk[(h+1)*36 + k] = p1;
    CTpk[(h+2)*36 + k] = p2; CTpk[(h+3)*36 + k] = p3;
    if (tid < 64) Sh[tid] = cshift[tid];
  }
  __syncthreads();

  // ---- static fragments (24 VGPRs)
  s16x8 aChi[2], aClo[2], bCThi[2];
#pragma unroll
  for (int i = 0; i < 2; ++i) {
    const unsigned* r0 = Cpk + (16*i + col)*36 + k0;
    uint4 u0 = *(const uint4*)r0, u1 = *(const uint4*)(r0 + 4);
    aChi[i] = unpack_hi(u0, u1); aClo[i] = unpack_lo(u0, u1);
    const unsigned* r1 = CTpk + (16*i + col)*36 + k0;
    uint4 t0 = *(const uint4*)r1, t1 = *(const uint4*)(r1 + 4);
    bCThi[i] = unpack_hi(t0, t1);
  }
  __syncthreads();   // Cpk/CTpk region now reusable as wave buffers

  unsigned* P = Pall + wave * 1152;          // per-wave [32][36] packed buffer
  const int tile = blockIdx.x * 4 + wave;
  const float* gx = resid + (size_t)tile * 1024;
  float* gout     = out   + (size_t)tile * 1024;

  // ---- stage X^T (packed hi/lo) : global coalesced read, transposed write
#pragma unroll
  for (int m = 0; m < 4; ++m) {
    int f = m * 64 + lane;
    int h = f >> 3, w = (f & 7) * 4;
    float4 v = ((const float4*)gx)[f];
    P[(w+0)*36 + h] = pack_split(v.x * 1023.0f);
    P[(w+1)*36 + h] = pack_split(v.y * 1023.0f);
    P[(w+2)*36 + h] = pack_split(v.z * 1023.0f);
    P[(w+3)*36 + h] = pack_split(v.w * 1023.0f);
  }
  // per-wave DS ops are processed in order: no barrier needed below.

  f32x4 acc[2][2];

  // ---- S1: tmp = C @ X  (3-product split)
#pragma unroll
  for (int mi = 0; mi < 2; ++mi)
#pragma unroll
    for (int nj = 0; nj < 2; ++nj) acc[mi][nj] = (f32x4)0.0f;
#pragma unroll
  for (int nj = 0; nj < 2; ++nj) {
    const unsigned* row = P + (16*nj + col)*36 + k0;
    uint4 u0 = *(const uint4*)row, u1 = *(const uint4*)(row + 4);
    s16x8 bh = unpack_hi(u0, u1), bl = unpack_lo(u0, u1);
#pragma unroll
    for (int mi = 0; mi < 2; ++mi) {
      acc[mi][nj] = __builtin_amdgcn_mfma_f32_16x16x32_bf16(aChi[mi], bh, acc[mi][nj], 0, 0, 0);
      acc[mi][nj] = __builtin_amdgcn_mfma_f32_16x16x32_bf16(aChi[mi], bl, acc[mi][nj], 0, 0, 0);
      acc[mi][nj] = __builtin_amdgcn_mfma_f32_16x16x32_bf16(aClo[mi], bh, acc[mi][nj], 0, 0, 0);
    }
  }
  // write tmp[k][w] packed (D row = k, D col = w)
#pragma unroll
  for (int mi = 0; mi < 2; ++mi)
#pragma unroll
    for (int nj = 0; nj < 2; ++nj)
#pragma unroll
      for (int r = 0; r < 4; ++r)
        P[(16*mi + 4*quad + r)*36 + 16*nj + col] = pack_split(acc[mi][nj][r]);

  // ---- S2: coeff^T = C @ tmp^T  (3-product split)
#pragma unroll
  for (int mi = 0; mi < 2; ++mi)
#pragma unroll
    for (int nj = 0; nj < 2; ++nj) acc[mi][nj] = (f32x4)0.0f;
#pragma unroll
  for (int nj = 0; nj < 2; ++nj) {
    const unsigned* row = P + (16*nj + col)*36 + k0;
    uint4 u0 = *(const uint4*)row, u1 = *(const uint4*)(row + 4);
    s16x8 bh = unpack_hi(u0, u1), bl = unpack_lo(u0, u1);
#pragma unroll
    for (int mi = 0; mi < 2; ++mi) {
      acc[mi][nj] = __builtin_amdgcn_mfma_f32_16x16x32_bf16(aChi[mi], bh, acc[mi][nj], 0, 0, 0);
      acc[mi][nj] = __builtin_amdgcn_mfma_f32_16x16x32_bf16(aChi[mi], bl, acc[mi][nj], 0, 0, 0);
      acc[mi][nj] = __builtin_amdgcn_mfma_f32_16x16x32_bf16(aClo[mi], bh, acc[mi][nj], 0, 0, 0);
    }
  }

  // ---- quant + dequant; write W^T[l][k] as bf16-hi (low16, high16 = 0)
#pragma unroll
  for (int mi = 0; mi < 2; ++mi)
#pragma unroll
    for (int nj = 0; nj < 2; ++nj)
#pragma unroll
      for (int r = 0; r < 4; ++r) {
        float c   = acc[mi][nj][r];              // coeff^T[l][k] = coeff[k][l]
        float qa  = floorf(fabsf(c) * (1.0f/QSTEP) + DZ);
        float ca  = qa * QSTEP;
        int   qi  = (int)qa; qi = qi > 63 ? 63 : qi;
        float cs  = Sh[qi];
        float ca2 = (qa + 1.0f) * QSTEP;
        float corr = ((1024.0f - cs) * ca + cs * ca2) * (1.0f/1024.0f);
        float cah  = (qa < 64.0f) ? corr : ca;
        float wv   = (c < 0.0f) ? -cah : cah;
        P[(16*mi + 4*quad + r)*36 + 16*nj + col] = rne_bf16(wv);
      }

  // ---- S3: tmp2 = C @ W  (single bf16 product)
#pragma unroll
  for (int mi = 0; mi < 2; ++mi)
#pragma unroll
    for (int nj = 0; nj < 2; ++nj) acc[mi][nj] = (f32x4)0.0f;
#pragma unroll
  for (int nj = 0; nj < 2; ++nj) {
    const unsigned* row = P + (16*nj + col)*36 + k0;
    uint4 u0 = *(const uint4*)row, u1 = *(const uint4*)(row + 4);
    s16x8 bh = unpack_hi(u0, u1);
#pragma unroll
    for (int mi = 0; mi < 2; ++mi)
      acc[mi][nj] = __builtin_amdgcn_mfma_f32_16x16x32_bf16(aChi[mi], bh, acc[mi][nj], 0, 0, 0);
  }
  // write tmp2[h][w] as bf16-hi
#pragma unroll
  for (int mi = 0; mi < 2; ++mi)
#pragma unroll
    for (int nj = 0; nj < 2; ++nj)
#pragma unroll
      for (int r = 0; r < 4; ++r)
        P[(16*mi + 4*quad + r)*36 + 16*nj + col] = rne_bf16(acc[mi][nj][r]);

  // ---- S4: rec = tmp2 @ C  (A = tmp2 from LDS, B = static C^T frags)
#pragma unroll
  for (int mi = 0; mi < 2; ++mi)
#pragma unroll
    for (int nj = 0; nj < 2; ++nj) acc[mi][nj] = (f32x4)0.0f;
#pragma unroll
  for (int mi = 0; mi < 2; ++mi) {
    const unsigned* row = P + (16*mi + col)*36 + k0;
    uint4 u0 = *(const uint4*)row, u1 = *(const uint4*)(row + 4);
    s16x8 ah = unpack_hi(u0, u1);
#pragma unroll
    for (int nj = 0; nj < 2; ++nj)
      acc[mi][nj] = __builtin_amdgcn_mfma_f32_16x16x32_bf16(ah, bCThi[nj], acc[mi][nj], 0, 0, 0);
  }

  // ---- epilogue: /1023 via LDS round-trip for coalesced float4 stores
  float* O = (float*)P;
#pragma unroll
  for (int mi = 0; mi < 2; ++mi)
#pragma unroll
    for (int nj = 0; nj < 2; ++nj)
#pragma unroll
      for (int r = 0; r < 4; ++r)
        O[(16*mi + 4*quad + r)*36 + 16*nj + col] = acc[mi][nj][r] * (1.0f/1023.0f);
#pragma unroll
  for (int m = 0; m < 4; ++m) {
    int f = m * 64 + lane;
    int h = f >> 3, w = (f & 7) * 4;
    float4 v = *(const float4*)(O + h*36 + w);
    ((float4*)gout)[f] = v;
  }
}

extern "C" void kernel_launch(void* const* d_in, const int* in_sizes, int n_in,
                              void* d_out, int out_size, void* d_ws, size_t ws_size,
                              hipStream_t stream) {
  const float* resid  = (const float*)d_in[0];   // [256,64,32,32]
  const float* dct    = (const float*)d_in[1];   // [32,32]
  const float* cshift = (const float*)d_in[2];   // [64]
  float* out = (float*)d_out;

  int tiles  = out_size / 1024;   // 16384
  int blocks = tiles / 4;         // 1 tile per wave, 4 waves per block
  vvc_mfma_kernel<<<blocks, 256, 0, stream>>>(resid, dct, cshift, out);
}

// Round 4
// 118.580 us; speedup vs baseline: 1.3315x; 1.0068x over previous
//
#include <hip/hip_runtime.h>

typedef float f32x4 __attribute__((ext_vector_type(4)));
typedef short s16x8 __attribute__((ext_vector_type(8)));

#define QSTEP 25.5f
#define DZ (85.0f/512.0f)

// round-to-nearest-even fp32 -> bf16 (low 16 bits)
__device__ __forceinline__ unsigned rne_bf16(float x) {
  unsigned u = __float_as_uint(x);
  return (u + 0x7FFFu + ((u >> 16) & 1u)) >> 16;
}

// One wave per 32x32 tile. Verified 16x16x32 bf16 MFMA layouts:
//   A[m=lane&15 (+16*mi)][k=quad*8+j] ; B[k=quad*8+j][n=lane&15 (+16*nj)]
//   D[row=quad*4+r (+16*mi)][col=lane&15 (+16*nj)]
// Chain (coeff = C@X@C^T ; W = quant(coeff) ; rec = (C@W@C)/1023):
//   S1:  tmp   = C @ X        A=C(hi,lo) static, B=X from GLOBAL frag loads (hi,lo)
//   S2:  coeff = tmp @ C^T    A=tmp (packed-split LDS plane), B=C^T == C-row frags
//   S3:  U^T   = W^T @ C^T    A=W^T (bf16 plane, b128), B=C^T == C-row frags
//   S4:  rec   = U @ C        A=U   (bf16 plane, b128), B=C == C-col frags
__global__ __launch_bounds__(256, 4) void vvc_mfma2_kernel(
    const float* __restrict__ resid,
    const float* __restrict__ dct,
    const float* __restrict__ cshift,
    float* __restrict__ out)
{
  __shared__ float shm[64 + 4 * 1152];   // Sh(64) + per-wave 1152-f32 buffer
  float* Sh   = shm;
  float* Pall = shm + 64;

  const int tid  = threadIdx.x;
  const int wave = tid >> 6;
  const int lane = tid & 63;
  const int col  = lane & 15;
  const int quad = lane >> 4;
  const int k0   = quad * 8;

  // ---- init: C hi/lo planes + C^T hi plane (u16, stride 40 => 16B-aligned rows)
  unsigned short* Chi  = (unsigned short*)Pall;        // [32][40]
  unsigned short* Clo  = Chi + 1280;
  unsigned short* CThi = Chi + 2560;
  {
    float4 cv = ((const float4*)dct)[tid];
    int k = tid >> 3, h = (tid & 7) * 4;
    float vals[4] = {cv.x, cv.y, cv.z, cv.w};
#pragma unroll
    for (int i = 0; i < 4; ++i) {
      unsigned hi = rne_bf16(vals[i]);
      float r = vals[i] - __uint_as_float(hi << 16);
      unsigned lo = rne_bf16(r);
      Chi[k * 40 + h + i]        = (unsigned short)hi;
      Clo[k * 40 + h + i]        = (unsigned short)lo;
      CThi[(h + i) * 40 + k]     = (unsigned short)hi;
    }
    if (tid < 64) Sh[tid] = cshift[tid];
  }
  __syncthreads();

  // ---- static fragments (24 VGPRs). aChi/aClo = C rows (A=C or B=C^T role),
  //      bCThi = C columns (B=C role).
  s16x8 aChi[2], aClo[2], bCThi[2];
#pragma unroll
  for (int i = 0; i < 2; ++i) {
    aChi[i]  = *(const s16x8*)(Chi  + (16 * i + col) * 40 + k0);
    aClo[i]  = *(const s16x8*)(Clo  + (16 * i + col) * 40 + k0);
    bCThi[i] = *(const s16x8*)(CThi + (16 * i + col) * 40 + k0);
  }
  __syncthreads();   // C planes dead; region becomes per-wave buffers

  float* Pw = Pall + wave * 1152;
  const int tile = blockIdx.x * 4 + wave;
  const float* gx = resid + (size_t)tile * 1024;
  float* gout     = out   + (size_t)tile * 1024;

  // ---- X directly from global in B-frag layout; truncation split (no LDS)
  s16x8 bXhi[2], bXlo[2];
#pragma unroll
  for (int nj = 0; nj < 2; ++nj) {
#pragma unroll
    for (int j = 0; j < 8; ++j) {
      float x = gx[(k0 + j) * 32 + nj * 16 + col] * 1023.0f;
      unsigned u  = __float_as_uint(x);
      float r = x - __uint_as_float(u & 0xFFFF0000u);   // exact residual
      bXhi[nj][j] = (short)(u >> 16);
      bXlo[nj][j] = (short)(__float_as_uint(r) >> 16);
    }
  }

  f32x4 acc[2][2];

  // ---- S1: tmp = C @ X  (3-product split)
#pragma unroll
  for (int mi = 0; mi < 2; ++mi)
#pragma unroll
    for (int nj = 0; nj < 2; ++nj) acc[mi][nj] = (f32x4)0.0f;
#pragma unroll
  for (int mi = 0; mi < 2; ++mi)
#pragma unroll
    for (int nj = 0; nj < 2; ++nj) {
      acc[mi][nj] = __builtin_amdgcn_mfma_f32_16x16x32_bf16(aChi[mi], bXhi[nj], acc[mi][nj], 0, 0, 0);
      acc[mi][nj] = __builtin_amdgcn_mfma_f32_16x16x32_bf16(aClo[mi], bXhi[nj], acc[mi][nj], 0, 0, 0);
      acc[mi][nj] = __builtin_amdgcn_mfma_f32_16x16x32_bf16(aChi[mi], bXlo[nj], acc[mi][nj], 0, 0, 0);
    }

  // ---- tmp packed-split plane T[k][w], f32 stride 36 (16B-aligned rows)
  unsigned* T = (unsigned*)Pw;
#pragma unroll
  for (int mi = 0; mi < 2; ++mi)
#pragma unroll
    for (int nj = 0; nj < 2; ++nj)
#pragma unroll
      for (int r = 0; r < 4; ++r) {
        float v = acc[mi][nj][r];
        unsigned u = __float_as_uint(v);
        float rr = v - __uint_as_float(u & 0xFFFF0000u);
        T[(16 * mi + 4 * quad + r) * 36 + 16 * nj + col] =
            (u >> 16) | (__float_as_uint(rr) & 0xFFFF0000u);
      }

  // ---- S2: coeff = tmp @ C^T  (A=tmp split, B=C^T via aChi/aClo)
  s16x8 tHi[2], tLo[2];
#pragma unroll
  for (int mi = 0; mi < 2; ++mi) {
    const unsigned* row = T + (16 * mi + col) * 36 + k0;
    uint4 u0 = *(const uint4*)row, u1 = *(const uint4*)(row + 4);
    s16x8 h, l;
    h[0]=(short)u0.x; h[1]=(short)u0.y; h[2]=(short)u0.z; h[3]=(short)u0.w;
    h[4]=(short)u1.x; h[5]=(short)u1.y; h[6]=(short)u1.z; h[7]=(short)u1.w;
    l[0]=(short)(u0.x>>16); l[1]=(short)(u0.y>>16); l[2]=(short)(u0.z>>16); l[3]=(short)(u0.w>>16);
    l[4]=(short)(u1.x>>16); l[5]=(short)(u1.y>>16); l[6]=(short)(u1.z>>16); l[7]=(short)(u1.w>>16);
    tHi[mi] = h; tLo[mi] = l;
  }
#pragma unroll
  for (int mi = 0; mi < 2; ++mi)
#pragma unroll
    for (int nj = 0; nj < 2; ++nj) acc[mi][nj] = (f32x4)0.0f;
#pragma unroll
  for (int mi = 0; mi < 2; ++mi)
#pragma unroll
    for (int nj = 0; nj < 2; ++nj) {
      acc[mi][nj] = __builtin_amdgcn_mfma_f32_16x16x32_bf16(tHi[mi], aChi[nj], acc[mi][nj], 0, 0, 0);
      acc[mi][nj] = __builtin_amdgcn_mfma_f32_16x16x32_bf16(tLo[mi], aChi[nj], acc[mi][nj], 0, 0, 0);
      acc[mi][nj] = __builtin_amdgcn_mfma_f32_16x16x32_bf16(tHi[mi], aClo[nj], acc[mi][nj], 0, 0, 0);
    }

  // ---- quant + dequant; write W^T[l][k] bf16 plane (u16 stride 40), b64-packed
  unsigned short* WT = (unsigned short*)Pw;
#pragma unroll
  for (int mi = 0; mi < 2; ++mi)
#pragma unroll
    for (int nj = 0; nj < 2; ++nj) {
      unsigned w16[4];
#pragma unroll
      for (int r = 0; r < 4; ++r) {
        float cc  = acc[mi][nj][r];
        float qa  = floorf(fabsf(cc) * (1.0f / QSTEP) + DZ);
        float ca  = qa * QSTEP;
        int   qi  = (int)qa; qi = qi > 63 ? 63 : qi;
        float cs  = Sh[qi];
        float ca2 = (qa + 1.0f) * QSTEP;
        float corr = ((1024.0f - cs) * ca + cs * ca2) * (1.0f / 1024.0f);
        float cah  = (qa < 64.0f) ? corr : ca;
        float wv   = (cc < 0.0f) ? -cah : cah;
        w16[r] = rne_bf16(wv);
      }
      uint2 pk; pk.x = w16[0] | (w16[1] << 16); pk.y = w16[2] | (w16[3] << 16);
      *(uint2*)(WT + (16 * nj + col) * 40 + 16 * mi + 4 * quad) = pk;
    }

  // ---- S3: U^T = W^T @ C^T  (A=W^T rows b128, B=C^T via aChi; single product)
  s16x8 wA[2];
#pragma unroll
  for (int mi = 0; mi < 2; ++mi)
    wA[mi] = *(const s16x8*)(WT + (16 * mi + col) * 40 + k0);
#pragma unroll
  for (int mi = 0; mi < 2; ++mi)
#pragma unroll
    for (int nj = 0; nj < 2; ++nj) acc[mi][nj] = (f32x4)0.0f;
#pragma unroll
  for (int mi = 0; mi < 2; ++mi)
#pragma unroll
    for (int nj = 0; nj < 2; ++nj)
      acc[mi][nj] = __builtin_amdgcn_mfma_f32_16x16x32_bf16(wA[mi], aChi[nj], acc[mi][nj], 0, 0, 0);

  // D = U^T[w][h] -> store U[h][w] plane ([D-col][D-row]): b64-packed over r
  unsigned short* U = WT;   // overlay (WT dead after wA loads)
#pragma unroll
  for (int mi = 0; mi < 2; ++mi)
#pragma unroll
    for (int nj = 0; nj < 2; ++nj) {
      unsigned u16v[4];
#pragma unroll
      for (int r = 0; r < 4; ++r) u16v[r] = rne_bf16(acc[mi][nj][r]);
      uint2 pk; pk.x = u16v[0] | (u16v[1] << 16); pk.y = u16v[2] | (u16v[3] << 16);
      *(uint2*)(U + (16 * nj + col) * 40 + 16 * mi + 4 * quad) = pk;
    }

  // ---- S4: rec = U @ C  (A=U rows b128, B=C via bCThi; single product)
  s16x8 uA[2];
#pragma unroll
  for (int mi = 0; mi < 2; ++mi)
    uA[mi] = *(const s16x8*)(U + (16 * mi + col) * 40 + k0);
#pragma unroll
  for (int mi = 0; mi < 2; ++mi)
#pragma unroll
    for (int nj = 0; nj < 2; ++nj) acc[mi][nj] = (f32x4)0.0f;
#pragma unroll
  for (int mi = 0; mi < 2; ++mi)
#pragma unroll
    for (int nj = 0; nj < 2; ++nj)
      acc[mi][nj] = __builtin_amdgcn_mfma_f32_16x16x32_bf16(uA[mi], bCThi[nj], acc[mi][nj], 0, 0, 0);

  // ---- epilogue: /1023 via O plane (f32 stride 36), coalesced float4 stores
  float* O = Pw;   // overlay (U dead after uA loads)
#pragma unroll
  for (int mi = 0; mi < 2; ++mi)
#pragma unroll
    for (int nj = 0; nj < 2; ++nj)
#pragma unroll
      for (int r = 0; r < 4; ++r)
        O[(16 * mi + 4 * quad + r) * 36 + 16 * nj + col] =
            acc[mi][nj][r] * (1.0f / 1023.0f);
#pragma unroll
  for (int m = 0; m < 4; ++m) {
    int f = m * 64 + lane;
    int h = f >> 3, w = (f & 7) * 4;
    ((float4*)gout)[f] = *(const float4*)(O + h * 36 + w);
  }
}

extern "C" void kernel_launch(void* const* d_in, const int* in_sizes, int n_in,
                              void* d_out, int out_size, void* d_ws, size_t ws_size,
                              hipStream_t stream) {
  const float* resid  = (const float*)d_in[0];   // [256,64,32,32]
  const float* dct    = (const float*)d_in[1];   // [32,32]
  const float* cshift = (const float*)d_in[2];   // [64]
  float* out = (float*)d_out;

  int tiles  = out_size / 1024;   // 16384
  int blocks = tiles / 4;         // 1 tile per wave, 4 waves per block
  vvc_mfma2_kernel<<<blocks, 256, 0, stream>>>(resid, dct, cshift, out);
}